// Round 2
// baseline (681.817 us; speedup 1.0000x reference)
//
#include <hip/hip_runtime.h>
#include <math.h>

#define BATCH 2048
#define N_TIME 2048
#define INPUT_SIZE 28
#define OUTPUT_SIZE 7
#define N_S 4
#define PERIOD 7
#define EMBED 9
#define SEAS_LEN (N_TIME + PERIOD)       // 2055
#define W_COUNT 288                      // len(range(0, 2014, 7))
#define WB_COUNT (W_COUNT * BATCH)       // 589824
#define INS_COLS 67                      // 28 + 35 + 4
#define TOT_COLS 74                      // 67 + 7
#define OUT0_SIZE (WB_COUNT * INS_COLS)
#define OUT1_SIZE (WB_COUNT * OUTPUT_SIZE)
#define LEV_SIZE (BATCH * N_TIME)
#define SEAS_SIZE (BATCH * SEAS_LEN)

// ---------------------------------------------------------------------------
// Phase 1: exponential-smoothing scan, LDS-tiled.
// Block = 256 threads owns 64 rows. Wave 0 (lanes 0..63, lane = row) runs the
// strictly-sequential recurrence out of LDS; waves 1..3 prefetch the next
// 64-row x 64-col Y tile into the other LDS buffer (coalesced, double-
// buffered); all 4 waves store the staged levels/seasonal tiles coalesced.
// LDS stride 65: scan access bank = (lane + k) % 32 -> 2-way aliasing (free).
// ---------------------------------------------------------------------------
__global__ __launch_bounds__(256) void es_scan(
    const float* __restrict__ Y, const int* __restrict__ idxs,
    const float* __restrict__ emb,
    float* __restrict__ levels, float* __restrict__ seasonal)
{
    __shared__ float yld[2][64][65];   // input tiles (double-buffered)
    __shared__ float ldsl[64][65];     // staged levels tile
    __shared__ float ldss[64][65];     // staged seasonal tile

    const int tid = threadIdx.x;
    const int r0  = blockIdx.x * 64;

    // wave-0 persistent scan state
    float lev = 0.f, lev_sms = 0.f, seas_sms = 0.f, oma = 0.f, oms = 0.f;
    float buf[PERIOD];
#pragma unroll
    for (int j = 0; j < PERIOD; ++j) buf[j] = 0.f;

    if (tid < 64) {
        const int b = r0 + tid;
        const float* e = emb + (size_t)idxs[b] * EMBED;
        lev_sms  = 1.0f / (1.0f + __expf(-e[0]));
        seas_sms = 1.0f / (1.0f + __expf(-e[1]));
        oma = 1.0f - lev_sms;
        oms = 1.0f - seas_sms;
        float is[PERIOD];
#pragma unroll
        for (int j = 0; j < PERIOD; ++j) is[j] = __expf(e[2 + j]);
        lev = Y[(size_t)b * N_TIME] / is[0];
        levels[(size_t)b * N_TIME] = lev;
        float* seab = seasonal + (size_t)b * SEAS_LEN;
#pragma unroll
        for (int j = 0; j < PERIOD; ++j) seab[j] = is[j];
        seab[PERIOD] = is[0];
        // shift-queue: buf[0] is the 's' consumed by the current step
#pragma unroll
        for (int j = 0; j < PERIOD; ++j) buf[j] = is[(j + 1) % PERIOD];
    } else {
        // load tile 0: Y cols 1..64
        for (int e2 = tid - 64; e2 < 4096; e2 += 192) {
            int row = e2 >> 6, col = e2 & 63;
            yld[0][row][col] = Y[(size_t)(r0 + row) * N_TIME + 1 + col];
        }
    }
    __syncthreads();

    for (int t = 0; t < 32; ++t) {
        const int k0  = t * 64;
        const int cnt = (t == 31) ? 63 : 64;   // steps 0..2046
        if (tid < 64) {
            // sequential scan of this tile. Critical chain: one fma on lev.
            // (tile 31 step 63 computes garbage from unloaded LDS; never stored)
#pragma unroll 8
            for (int k = 0; k < 64; ++k) {
                float y  = yld[t & 1][tid][k];
                float s  = buf[0];
                float nl = fmaf(oma, lev, lev_sms * (y * __builtin_amdgcn_rcpf(s)));
                float ns = fmaf(oms, s,   seas_sms * (y * __builtin_amdgcn_rcpf(nl)));
#pragma unroll
                for (int q = 0; q < PERIOD - 1; ++q) buf[q] = buf[q + 1];
                buf[PERIOD - 1] = ns;
                lev = nl;
                ldsl[tid][k] = nl;
                ldss[tid][k] = ns;
            }
        } else if (t < 31) {
            // prefetch tile t+1: Y cols 64(t+1)+1 ..
            const int cn = (t == 30) ? 63 : 64;
            const int c0 = k0 + 65;
            for (int e2 = tid - 64; e2 < 4096; e2 += 192) {
                int row = e2 >> 6, col = e2 & 63;
                if (col < cn)
                    yld[(t + 1) & 1][row][col] =
                        Y[(size_t)(r0 + row) * N_TIME + c0 + col];
            }
        }
        __syncthreads();
        // coalesced store of the staged tiles
        for (int e2 = tid; e2 < 4096; e2 += 256) {
            int row = e2 >> 6, col = e2 & 63;
            if (col < cnt) {
                levels[(size_t)(r0 + row) * N_TIME + k0 + 1 + col]   = ldsl[row][col];
                seasonal[(size_t)(r0 + row) * SEAS_LEN + k0 + 8 + col] = ldss[row][col];
            }
        }
        __syncthreads();
    }
}

// ---------------------------------------------------------------------------
// Phase 2: window materialization, segmented grid (every segment size is a
// multiple of 256 -> every block is branch-uniform; no wave divergence).
// ---------------------------------------------------------------------------
#define SEG_A (WB_COUNT * INPUT_SIZE)   // 16,515,072  log insample
#define SEG_B (WB_COUNT * 35)           // 20,643,840  X copy
#define SEG_C (WB_COUNT * N_S)          //  2,359,296  S broadcast
#define SEG_D (WB_COUNT * OUTPUT_SIZE)  //  4,128,768  outsample

__global__ __launch_bounds__(256) void es_windows(
    const float* __restrict__ Y, const float* __restrict__ X,
    const float* __restrict__ S, const float* __restrict__ levels,
    const float* __restrict__ seasonal,
    float* __restrict__ out0, float* __restrict__ out1)
{
    int gid = blockIdx.x * 256 + threadIdx.x;
    if (gid < SEG_A) {
        int wb = gid / INPUT_SIZE;
        int j  = gid - wb * INPUT_SIZE;
        int w  = wb >> 11, b = wb & (BATCH - 1);
        int t  = w * 7 + j;
        float y  = Y[b * N_TIME + t];
        float lv = levels[b * N_TIME + w * 7 + INPUT_SIZE - 1];
        float sv = seasonal[b * SEAS_LEN + t];
        out0[wb * INS_COLS + j] = __logf(y * __builtin_amdgcn_rcpf(lv * sv));
    } else if (gid < SEG_A + SEG_B) {
        int e  = gid - SEG_A;
        int wb = e / 35;
        int m  = e - wb * 35;
        int w  = wb >> 11, b = wb & (BATCH - 1);
        out0[wb * INS_COLS + INPUT_SIZE + m] = X[b * N_TIME + w * 7 + m];
    } else if (gid < SEG_A + SEG_B + SEG_C) {
        int e  = gid - (SEG_A + SEG_B);
        int wb = e >> 2;
        int m  = e & 3;
        out0[wb * INS_COLS + 63 + m] = S[(wb & (BATCH - 1)) * N_S + m];
    } else {
        int e  = gid - (SEG_A + SEG_B + SEG_C);
        int wb = e / 7;
        int m  = e - wb * 7;
        int w  = wb >> 11, b = wb & (BATCH - 1);
        out1[e] = Y[b * N_TIME + w * 7 + INPUT_SIZE + m];
    }
}

extern "C" void kernel_launch(void* const* d_in, const int* in_sizes, int n_in,
                              void* d_out, int out_size, void* d_ws, size_t ws_size,
                              hipStream_t stream) {
    const float* S    = (const float*)d_in[0];
    const float* Y    = (const float*)d_in[1];
    const float* X    = (const float*)d_in[2];
    const int*   idxs = (const int*)d_in[3];
    const float* emb  = (const float*)d_in[4];

    float* out      = (float*)d_out;
    float* out_ins  = out;                                    // (W,B,67)
    float* out_outs = out + OUT0_SIZE;                        // (W,B,7)
    float* levels   = out + OUT0_SIZE + OUT1_SIZE;            // (B,2048)
    float* seasonal = out + OUT0_SIZE + OUT1_SIZE + LEV_SIZE; // (B,2055)

    es_scan<<<BATCH / 64, 256, 0, stream>>>(Y, idxs, emb, levels, seasonal);

    const int total = SEG_A + SEG_B + SEG_C + SEG_D;          // WB_COUNT * 74
    es_windows<<<total / 256, 256, 0, stream>>>(
        Y, X, S, levels, seasonal, out_ins, out_outs);
}

// Round 3
// 424.334 us; speedup vs baseline: 1.6068x; 1.6068x over previous
//
#include <hip/hip_runtime.h>
#include <math.h>

#define BATCH 2048
#define N_TIME 2048
#define INPUT_SIZE 28
#define OUTPUT_SIZE 7
#define N_S 4
#define PERIOD 7
#define EMBED 9
#define SEAS_LEN (N_TIME + PERIOD)       // 2055
#define W_COUNT 288                      // len(range(0, 2014, 7))
#define WB_COUNT (W_COUNT * BATCH)       // 589824
#define INS_COLS 67                      // 28 + 35 + 4
#define OUT0_SIZE (WB_COUNT * INS_COLS)  // 39,518,208 (multiple of 256)
#define OUT1_SIZE (WB_COUNT * OUTPUT_SIZE) // 4,128,768 (multiple of 256)
#define LEV_SIZE (BATCH * N_TIME)
#define SEAS_SIZE (BATCH * SEAS_LEN)

// ---------------------------------------------------------------------------
// Phase 1 scan: one wave (64 threads) per block, 32 blocks, NO barriers across
// waves of different roles. Lane = row. Per 64-step chunk:
//   - prefetch next chunk's Y (per-lane aligned float4, double-buffered)
//   - 64 sequential steps (critical chain: 1 fma on lev), results into LDS
//     tiles tl/ts (stride 65 -> conflict-free writes)
//   - transpose-store the tiles coalesced (float4 rows for levels; scalar
//     coalesced for seasonal, whose odd row stride 2055 forbids 16B align)
// tl col k <-> levels col t = base+k (col 0 = carry-in lev, so levels[b][0]
// comes out of the tile too). ts col k <-> seasonal col base+8+k.
// ---------------------------------------------------------------------------
struct ScanState {
    float lev, lev_sms, seas_sms, oma, oms;
    float buf[PERIOD];
};

template<bool PREF, bool LAST>
__device__ __forceinline__ void scan_chunk(
    int base, int l, int r0, int jr, int km,
    const float* __restrict__ Yb,
    float (&cur)[64], float (&nxt)[64],
    float (*__restrict__ tl)[65], float (*__restrict__ ts)[65],
    ScanState& st,
    float* __restrict__ levels, float* __restrict__ seasonal)
{
    if (PREF) {
#pragma unroll
        for (int k = 0; k < 64; k += 4)
            *(float4*)&nxt[k] = *(const float4*)(Yb + base + 64 + k);
    }
    tl[l][0] = st.lev;                 // carry-in: levels col `base`
#pragma unroll
    for (int k = 0; k < 64; ++k) {
        if (!LAST || k < 63) {         // last chunk has 63 steps
            float y  = (k < 63) ? cur[k + 1] : nxt[0];
            float s0 = st.buf[0];
            float nl = fmaf(st.oma, st.lev,
                            st.lev_sms * (y * __builtin_amdgcn_rcpf(s0)));
            float ns = fmaf(st.oms, s0,
                            st.seas_sms * (y * __builtin_amdgcn_rcpf(nl)));
#pragma unroll
            for (int q = 0; q < PERIOD - 1; ++q) st.buf[q] = st.buf[q + 1];
            st.buf[PERIOD - 1] = ns;
            st.lev = nl;
            tl[l][k + 1] = nl;         // levels col base+k+1
            ts[l][k]     = ns;         // seasonal col base+8+k
        }
    }
    __syncthreads();                   // single wave: just an LDS drain
#pragma unroll
    for (int j0 = 0; j0 < 64; j0 += 4) {
        int j = j0 + jr;               // tile row = local batch row
        float vl[4], vs[4];
#pragma unroll
        for (int i = 0; i < 4; ++i) { vl[i] = tl[j][km + i]; vs[i] = ts[j][km + i]; }
        float4 v4; v4.x = vl[0]; v4.y = vl[1]; v4.z = vl[2]; v4.w = vl[3];
        *(float4*)(levels + (size_t)(r0 + j) * N_TIME + base + km) = v4;
        float* srow = seasonal + (size_t)(r0 + j) * SEAS_LEN + base + 8 + km;
#pragma unroll
        for (int i = 0; i < 4; ++i)
            if (!LAST || (km + i) < 63) srow[i] = vs[i];  // col 2054 is last
    }
    __syncthreads();
}

__global__ __launch_bounds__(64) void es_scan(
    const float* __restrict__ Y, const int* __restrict__ idxs,
    const float* __restrict__ emb,
    float* __restrict__ levels, float* __restrict__ seasonal)
{
    __shared__ float tl[64][65];
    __shared__ float ts[64][65];
    const int l  = threadIdx.x;
    const int r0 = blockIdx.x * 64;
    const int b  = r0 + l;
    const float* Yb = Y + (size_t)b * N_TIME;
    const int jr = l >> 4;
    const int km = (l & 15) * 4;

    const float* e = emb + (size_t)idxs[b] * EMBED;
    ScanState st;
    st.lev_sms  = 1.0f / (1.0f + __expf(-e[0]));
    st.seas_sms = 1.0f / (1.0f + __expf(-e[1]));
    st.oma = 1.0f - st.lev_sms;
    st.oms = 1.0f - st.seas_sms;
    float is[PERIOD];
#pragma unroll
    for (int j = 0; j < PERIOD; ++j) is[j] = __expf(e[2 + j]);
    st.lev = Yb[0] / is[0];

    float* seab = seasonal + (size_t)b * SEAS_LEN;
#pragma unroll
    for (int j = 0; j < PERIOD; ++j) seab[j] = is[j];
    seab[PERIOD] = is[0];
#pragma unroll
    for (int j = 0; j < PERIOD; ++j) st.buf[j] = is[(j + 1) % PERIOD];

    float ya[64], yb2[64];
#pragma unroll
    for (int k = 0; k < 64; k += 4)
        *(float4*)&ya[k] = *(const float4*)(Yb + k);

    // chunks 0..29 in pairs (ping-pong the y double-buffer), then 30, 31
#pragma unroll 1
    for (int cc = 0; cc < 15; ++cc) {
        scan_chunk<true, false>(cc * 128,      l, r0, jr, km, Yb, ya, yb2, tl, ts, st, levels, seasonal);
        scan_chunk<true, false>(cc * 128 + 64, l, r0, jr, km, Yb, yb2, ya, tl, ts, st, levels, seasonal);
    }
    scan_chunk<true,  false>(1920, l, r0, jr, km, Yb, ya, yb2, tl, ts, st, levels, seasonal);
    scan_chunk<false, true >(1984, l, r0, jr, km, Yb, yb2, ya, tl, ts, st, levels, seasonal);
}

// ---------------------------------------------------------------------------
// Phase 2: window materialization. gid is a LINEAR index into out0 (then out1)
// -> every store consecutive, full 64B lines, no gaps. Branch divergence
// within a wave (~2.5 small bodies) is cheap; all reads are L3-resident.
// Both segments are multiples of 256 -> block-aligned split.
// ---------------------------------------------------------------------------
__global__ __launch_bounds__(256) void es_windows(
    const float* __restrict__ Y, const float* __restrict__ X,
    const float* __restrict__ S, const float* __restrict__ levels,
    const float* __restrict__ seasonal,
    float* __restrict__ out0, float* __restrict__ out1)
{
    int gid = blockIdx.x * 256 + threadIdx.x;
    if (gid < OUT0_SIZE) {
        unsigned u  = (unsigned)gid;
        unsigned wb = u / 67u;
        int j  = (int)(u - wb * 67u);
        int w  = (int)(wb >> 11);
        int b  = (int)(wb & (BATCH - 1));
        int t0 = w * 7;
        float v;
        if (j < INPUT_SIZE) {
            float y  = Y[b * N_TIME + t0 + j];
            float lv = levels[b * N_TIME + t0 + INPUT_SIZE - 1];
            float sv = seasonal[b * SEAS_LEN + t0 + j];
            v = __logf(y * __builtin_amdgcn_rcpf(lv * sv));
        } else if (j < 63) {
            v = X[b * N_TIME + t0 + (j - INPUT_SIZE)];
        } else {
            v = S[b * N_S + (j - 63)];
        }
        out0[gid] = v;
    } else {
        unsigned e  = (unsigned)(gid - OUT0_SIZE);
        unsigned wb = e / 7u;
        int m  = (int)(e - wb * 7u);
        int w  = (int)(wb >> 11);
        int b  = (int)(wb & (BATCH - 1));
        out1[e] = Y[b * N_TIME + w * 7 + INPUT_SIZE + m];
    }
}

extern "C" void kernel_launch(void* const* d_in, const int* in_sizes, int n_in,
                              void* d_out, int out_size, void* d_ws, size_t ws_size,
                              hipStream_t stream) {
    const float* S    = (const float*)d_in[0];
    const float* Y    = (const float*)d_in[1];
    const float* X    = (const float*)d_in[2];
    const int*   idxs = (const int*)d_in[3];
    const float* emb  = (const float*)d_in[4];

    float* out      = (float*)d_out;
    float* out_ins  = out;                                    // (W,B,67)
    float* out_outs = out + OUT0_SIZE;                        // (W,B,7)
    float* levels   = out + OUT0_SIZE + OUT1_SIZE;            // (B,2048)
    float* seasonal = out + OUT0_SIZE + OUT1_SIZE + LEV_SIZE; // (B,2055)

    es_scan<<<BATCH / 64, 64, 0, stream>>>(Y, idxs, emb, levels, seasonal);

    const int total = OUT0_SIZE + OUT1_SIZE;                  // 43,646,976
    es_windows<<<total / 256, 256, 0, stream>>>(
        Y, X, S, levels, seasonal, out_ins, out_outs);
}